// Round 3
// baseline (427.285 us; speedup 1.0000x reference)
//
#include <hip/hip_runtime.h>
#include <math.h>

#define B 1024
#define FRAMES 31
#define NFFT 2048
#define NHALF 1024
#define NH 256
#define TWO_PI 6.28318530717958647692f

#define KSPLIT 16
#define KRANGE (NHALF / KSPLIT)  // 64
#define BT 32
#define JP 260                   // pad pitch for Wf tile [k][j]
#define HP 36                    // pad pitch for h tile  [k][b]

// ---------------- K0: fold W1 for real-FFT symmetry ----------------
// Wf[j][k] = W1[j][k] + (k ? W1[j][2048-k] : 0), k=0..1023 ; Wc[j] = W1[j][1024]
__global__ __launch_bounds__(256) void k_fold(const float* __restrict__ W1,
                                              float* __restrict__ Wf,
                                              float* __restrict__ Wc) {
    int idx = blockIdx.x * 256 + threadIdx.x;   // 0..262143
    int j = idx >> 10;
    int k = idx & 1023;
    float v = W1[(size_t)j * NFFT + k];
    if (k) v += W1[(size_t)j * NFFT + (NFFT - k)];
    Wf[idx] = v;
    if (k == 0) Wc[j] = W1[(size_t)j * NFFT + 1024];
}

// ---------------- K1: frame-mean + real-input FFT via 1024-pt complex FFT ----------------
// hh[b][k] = Re X_k, k=0..1023 ; h1024[b] = Re X_1024
__global__ __launch_bounds__(256) void k_mean_rfft(const float* __restrict__ x,
                                                   float* __restrict__ hh,
                                                   float* __restrict__ h1024) {
    __shared__ float xs[NFFT];
    __shared__ float zr[NHALF];
    __shared__ float zi[NHALF];
    __shared__ float ct[NFFT];     // ct[i] = cos(2*pi*i/2048)
    const int tid = threadIdx.x;
    const int b = blockIdx.x;
    const float* xr = x + (size_t)b * (FRAMES * NFFT);

#pragma unroll
    for (int s = 0; s < 8; ++s) {
        int i = tid + (s << 8);
        ct[i] = cosf(TWO_PI * (float)i / (float)NFFT);
    }

    // frame mean, coalesced
    float acc[8];
#pragma unroll
    for (int s = 0; s < 8; ++s) acc[s] = 0.f;
    for (int f = 0; f < FRAMES; ++f) {
        const float* fr = xr + f * NFFT;
#pragma unroll
        for (int s = 0; s < 8; ++s) acc[s] += fr[tid + (s << 8)];
    }
    const float inv = 1.0f / (float)FRAMES;
#pragma unroll
    for (int s = 0; s < 8; ++s) xs[tid + (s << 8)] = acc[s] * inv;
    __syncthreads();

    // pack z_n = xs[2n] + i*xs[2n+1], store bit-reversed (10-bit) for DIT
#pragma unroll
    for (int m = 0; m < 4; ++m) {
        int n = tid + (m << 8);                 // 0..1023
        int rv = __brev((unsigned)n) >> 22;     // 10-bit reverse
        zr[rv] = xs[2 * n];
        zi[rv] = xs[2 * n + 1];
    }
    __syncthreads();

    // 10 radix-2 DIT stages on 1024 points (512 butterflies, 2/thread)
    for (int st = 1; st <= 10; ++st) {
        const int half = 1 << (st - 1);
        const int tsh = 11 - st;                // angle idx in 1/2048 units
#pragma unroll
        for (int s = 0; s < 2; ++s) {
            int idx = tid + (s << 8);           // 0..511
            int j = idx & (half - 1);
            int base = ((idx >> (st - 1)) << st) + j;
            int ti = j << tsh;
            float wr = ct[ti];
            float wi = -ct[(ti + 1536) & (NFFT - 1)];   // -sin
            float ar = zr[base], ai = zi[base];
            float br = zr[base + half], bi = zi[base + half];
            float tr = wr * br - wi * bi;
            float tq = wr * bi + wi * br;
            zr[base] = ar + tr;
            zi[base] = ai + tq;
            zr[base + half] = ar - tr;
            zi[base + half] = ai - tq;
        }
        __syncthreads();
    }

    // untangle: Re X_k = (a+c)/2 + cos*(b+d)/2 - sin*(a-c)/2
    float* ho = hh + (size_t)b * NHALF;
#pragma unroll
    for (int m = 0; m < 4; ++m) {
        int k = tid + (m << 8);
        int km = (NHALF - k) & (NHALF - 1);
        float a = zr[k], bb = zi[k];
        float c = zr[km], d = zi[km];
        float cosv = ct[k];
        float sinv = ct[(k + 1536) & (NFFT - 1)];
        ho[k] = 0.5f * ((a + c) + cosv * (bb + d) - sinv * (a - c));
    }
    if (tid == 0) h1024[b] = zr[0] - zi[0];
}

// ---------------- K2: partial GEMM yp[sp][b][j] = sum_{k in split} hh[b][k]*Wf[j][k]
__global__ __launch_bounds__(256) void k_gemm1(const float* __restrict__ hh,
                                               const float* __restrict__ Wf,
                                               float* __restrict__ yp) {
    __shared__ float Ws[32 * JP];
    __shared__ float hs[32 * HP];
    const int tid = threadIdx.x;
    const int b0 = blockIdx.x * BT;
    const int kb0 = blockIdx.y * KRANGE;

    const int j0 = (tid & 63) * 4;
    const int bo = (tid >> 6) * 8;

    float acc[8][4];
#pragma unroll
    for (int i = 0; i < 8; ++i)
#pragma unroll
        for (int q = 0; q < 4; ++q) acc[i][q] = 0.f;

    for (int kc = 0; kc < KRANGE; kc += 32) {
        const int kb = kb0 + kc;
#pragma unroll
        for (int s = 0; s < 8; ++s) {
            int f = tid + (s << 8);
            int j = f >> 3;
            int k4 = f & 7;
            float4 v = *(const float4*)(Wf + (size_t)j * NHALF + kb + k4 * 4);
            Ws[(k4 * 4 + 0) * JP + j] = v.x;
            Ws[(k4 * 4 + 1) * JP + j] = v.y;
            Ws[(k4 * 4 + 2) * JP + j] = v.z;
            Ws[(k4 * 4 + 3) * JP + j] = v.w;
        }
        {
            int bb = tid >> 3;
            int k4 = tid & 7;
            float4 v = *(const float4*)(hh + (size_t)(b0 + bb) * NHALF + kb + k4 * 4);
            hs[(k4 * 4 + 0) * HP + bb] = v.x;
            hs[(k4 * 4 + 1) * HP + bb] = v.y;
            hs[(k4 * 4 + 2) * HP + bb] = v.z;
            hs[(k4 * 4 + 3) * HP + bb] = v.w;
        }
        __syncthreads();

#pragma unroll 8
        for (int k = 0; k < 32; ++k) {
            float4 w = *(const float4*)&Ws[k * JP + j0];
            float4 hA = *(const float4*)&hs[k * HP + bo];
            float4 hB = *(const float4*)&hs[k * HP + bo + 4];
            acc[0][0] = fmaf(hA.x, w.x, acc[0][0]); acc[0][1] = fmaf(hA.x, w.y, acc[0][1]);
            acc[0][2] = fmaf(hA.x, w.z, acc[0][2]); acc[0][3] = fmaf(hA.x, w.w, acc[0][3]);
            acc[1][0] = fmaf(hA.y, w.x, acc[1][0]); acc[1][1] = fmaf(hA.y, w.y, acc[1][1]);
            acc[1][2] = fmaf(hA.y, w.z, acc[1][2]); acc[1][3] = fmaf(hA.y, w.w, acc[1][3]);
            acc[2][0] = fmaf(hA.z, w.x, acc[2][0]); acc[2][1] = fmaf(hA.z, w.y, acc[2][1]);
            acc[2][2] = fmaf(hA.z, w.z, acc[2][2]); acc[2][3] = fmaf(hA.z, w.w, acc[2][3]);
            acc[3][0] = fmaf(hA.w, w.x, acc[3][0]); acc[3][1] = fmaf(hA.w, w.y, acc[3][1]);
            acc[3][2] = fmaf(hA.w, w.z, acc[3][2]); acc[3][3] = fmaf(hA.w, w.w, acc[3][3]);
            acc[4][0] = fmaf(hB.x, w.x, acc[4][0]); acc[4][1] = fmaf(hB.x, w.y, acc[4][1]);
            acc[4][2] = fmaf(hB.x, w.z, acc[4][2]); acc[4][3] = fmaf(hB.x, w.w, acc[4][3]);
            acc[5][0] = fmaf(hB.y, w.x, acc[5][0]); acc[5][1] = fmaf(hB.y, w.y, acc[5][1]);
            acc[5][2] = fmaf(hB.y, w.z, acc[5][2]); acc[5][3] = fmaf(hB.y, w.w, acc[5][3]);
            acc[6][0] = fmaf(hB.z, w.x, acc[6][0]); acc[6][1] = fmaf(hB.z, w.y, acc[6][1]);
            acc[6][2] = fmaf(hB.z, w.z, acc[6][2]); acc[6][3] = fmaf(hB.z, w.w, acc[6][3]);
            acc[7][0] = fmaf(hB.w, w.x, acc[7][0]); acc[7][1] = fmaf(hB.w, w.y, acc[7][1]);
            acc[7][2] = fmaf(hB.w, w.z, acc[7][2]); acc[7][3] = fmaf(hB.w, w.w, acc[7][3]);
        }
        __syncthreads();
    }

    float* yo = yp + (size_t)blockIdx.y * (B * NH);
#pragma unroll
    for (int i = 0; i < 8; ++i) {
        float4 v = make_float4(acc[i][0], acc[i][1], acc[i][2], acc[i][3]);
        *(float4*)(yo + (size_t)(b0 + bo + i) * NH + j0) = v;
    }
}

// ---------------- K3: fused reduce + bias/relu + layer2 + layer3 + sigmoid ----------------
// One block per 4 batch rows.
__global__ __launch_bounds__(256) void k_tail(const float* __restrict__ yp,
                                              const float* __restrict__ b1,
                                              const float* __restrict__ Wc,
                                              const float* __restrict__ h1024,
                                              const float* __restrict__ W2,
                                              const float* __restrict__ b2,
                                              const float* __restrict__ W3,
                                              const float* __restrict__ b3,
                                              float* __restrict__ out) {
    __shared__ float ys[4 * NH];
    __shared__ float w2s[NH * 36];   // [j][k-chunk 32, pitch 36]
    __shared__ float red[4 * NH];
    const int tid = threadIdx.x;
    const int b0 = blockIdx.x * 4;

    // phase A: sum partials, + b1 + h1024*Wc, relu -> ys
    {
        int r = tid >> 6;
        int j = (tid & 63) * 4;
        const float* base = yp + (size_t)(b0 + r) * NH + j;
        float4 a = *(const float4*)(base);
#pragma unroll
        for (int s = 1; s < KSPLIT; ++s) {
            float4 v = *(const float4*)(base + (size_t)s * (B * NH));
            a.x += v.x; a.y += v.y; a.z += v.z; a.w += v.w;
        }
        float4 bb = *(const float4*)(b1 + j);
        float4 wc = *(const float4*)(Wc + j);
        float hq = h1024[b0 + r];
        a.x = fmaxf(a.x + bb.x + hq * wc.x, 0.f);
        a.y = fmaxf(a.y + bb.y + hq * wc.y, 0.f);
        a.z = fmaxf(a.z + bb.z + hq * wc.z, 0.f);
        a.w = fmaxf(a.w + bb.w + hq * wc.w, 0.f);
        *(float4*)(ys + r * NH + j) = a;
    }
    __syncthreads();

    // phase B: y2[r][tid] = sum_k ys[r][k] * W2[tid][k], chunked through LDS
    float a2[4] = {0.f, 0.f, 0.f, 0.f};
    for (int kc = 0; kc < NH; kc += 32) {
#pragma unroll
        for (int s = 0; s < 8; ++s) {
            int f = tid + (s << 8);
            int j = f >> 3;
            int k4 = f & 7;
            float4 v = *(const float4*)(W2 + (size_t)j * NH + kc + k4 * 4);
            *(float4*)(w2s + j * 36 + k4 * 4) = v;
        }
        __syncthreads();
#pragma unroll
        for (int k4 = 0; k4 < 8; ++k4) {
            float4 w = *(const float4*)(w2s + tid * 36 + k4 * 4);
#pragma unroll
            for (int r = 0; r < 4; ++r) {
                float4 y = *(const float4*)(ys + r * NH + kc + k4 * 4);
                a2[r] = fmaf(w.x, y.x, a2[r]);
                a2[r] = fmaf(w.y, y.y, a2[r]);
                a2[r] = fmaf(w.z, y.z, a2[r]);
                a2[r] = fmaf(w.w, y.w, a2[r]);
            }
        }
        __syncthreads();
    }

    // phase C: relu, scale by W3, tree-reduce, sigmoid
    float w3 = W3[tid];
    float bb2 = b2[tid];
#pragma unroll
    for (int r = 0; r < 4; ++r)
        red[r * NH + tid] = fmaxf(a2[r] + bb2, 0.f) * w3;
    __syncthreads();
    for (int s = 128; s > 0; s >>= 1) {
        if (tid < s) {
#pragma unroll
            for (int r = 0; r < 4; ++r)
                red[r * NH + tid] += red[r * NH + tid + s];
        }
        __syncthreads();
    }
    if (tid < 4)
        out[b0 + tid] = 1.f / (1.f + expf(-(red[tid * NH] + b3[0])));
}

extern "C" void kernel_launch(void* const* d_in, const int* in_sizes, int n_in,
                              void* d_out, int out_size, void* d_ws, size_t ws_size,
                              hipStream_t stream) {
    const float* x  = (const float*)d_in[0];
    const float* W1 = (const float*)d_in[1];
    const float* b1 = (const float*)d_in[2];
    const float* W2 = (const float*)d_in[3];
    const float* b2 = (const float*)d_in[4];
    const float* W3 = (const float*)d_in[5];
    const float* b3 = (const float*)d_in[6];
    float* out = (float*)d_out;

    char* ws = (char*)d_ws;
    float* hh    = (float*)(ws);                   //  4 MB [1024][1024]
    float* yp    = (float*)(ws + (4u  << 20));     // 16 MB [16][1024][256]
    float* Wf    = (float*)(ws + (20u << 20));     //  1 MB [256][1024]
    float* Wc    = (float*)(ws + (21u << 20));     //  1 KB [256]
    float* h1024 = (float*)(ws + (21u << 20) + 65536);  // 4 KB [1024]

    hipLaunchKernelGGL(k_fold,      dim3(1024),   dim3(256), 0, stream, W1, Wf, Wc);
    hipLaunchKernelGGL(k_mean_rfft, dim3(B),      dim3(256), 0, stream, x, hh, h1024);
    hipLaunchKernelGGL(k_gemm1,     dim3(32, 16), dim3(256), 0, stream, hh, Wf, yp);
    hipLaunchKernelGGL(k_tail,      dim3(256),    dim3(256), 0, stream, yp, b1, Wc, h1024,
                       W2, b2, W3, b3, out);
}

// Round 4
// 419.397 us; speedup vs baseline: 1.0188x; 1.0188x over previous
//
#include <hip/hip_runtime.h>
#include <math.h>

#define B 1024
#define FRAMES 31
#define NFFT 2048
#define NHALF 1024
#define NH 256
#define TWO_PI 6.28318530717958647692f

#define KSPLIT 16
#define KRANGE (NHALF / KSPLIT)  // 64
#define BT 32
#define JP 260                   // pad pitch for Wf tile [k][j]
#define HP 36                    // pad pitch for h tile  [k][b]

// ---------------- K0: fold W1 for real-FFT symmetry ----------------
// Wf[j][k] = W1[j][k] + (k ? W1[j][2048-k] : 0), k=0..1023 ; Wc[j] = W1[j][1024]
__global__ __launch_bounds__(256) void k_fold(const float* __restrict__ W1,
                                              float* __restrict__ Wf,
                                              float* __restrict__ Wc) {
    int idx = blockIdx.x * 256 + threadIdx.x;   // 0..262143
    int j = idx >> 10;
    int k = idx & 1023;
    float v = W1[(size_t)j * NFFT + k];
    if (k) v += W1[(size_t)j * NFFT + (NFFT - k)];
    Wf[idx] = v;
    if (k == 0) Wc[j] = W1[(size_t)j * NFFT + 1024];
}

// ---------------- K1: frame-mean + real-input FFT via 1024-pt complex FFT ----------------
// hh[b][k] = Re X_k, k=0..1023 ; h1024[b] = Re X_1024
// Mean phase uses float4 loads (1 KB/wave-inst), fully unrolled over 31 frames
// so the compiler can keep many loads in flight (common-mistake #2 fix).
__global__ __launch_bounds__(256) void k_mean_rfft(const float* __restrict__ x,
                                                   float* __restrict__ hh,
                                                   float* __restrict__ h1024) {
    __shared__ float xs[NFFT];
    __shared__ float zr[NHALF];
    __shared__ float zi[NHALF];
    __shared__ float ct[NFFT];     // ct[i] = cos(2*pi*i/2048)
    const int tid = threadIdx.x;
    const int b = blockIdx.x;
    const float4* xr = (const float4*)(x + (size_t)b * (FRAMES * NFFT));  // 512 f4/frame

#pragma unroll
    for (int s = 0; s < 8; ++s) {
        int i = tid + (s << 8);
        ct[i] = cosf(TWO_PI * (float)i / (float)NFFT);
    }

    // frame mean: thread owns f4-columns tid and tid+256
    float4 a0 = {0.f, 0.f, 0.f, 0.f};
    float4 a1 = {0.f, 0.f, 0.f, 0.f};
#pragma unroll
    for (int f = 0; f < FRAMES; ++f) {
        float4 v0 = xr[f * 512 + tid];
        float4 v1 = xr[f * 512 + tid + 256];
        a0.x += v0.x; a0.y += v0.y; a0.z += v0.z; a0.w += v0.w;
        a1.x += v1.x; a1.y += v1.y; a1.z += v1.z; a1.w += v1.w;
    }
    const float inv = 1.0f / (float)FRAMES;
    a0.x *= inv; a0.y *= inv; a0.z *= inv; a0.w *= inv;
    a1.x *= inv; a1.y *= inv; a1.z *= inv; a1.w *= inv;
    ((float4*)xs)[tid] = a0;
    ((float4*)xs)[tid + 256] = a1;
    __syncthreads();

    // pack z_n = xs[2n] + i*xs[2n+1], store bit-reversed (10-bit) for DIT
#pragma unroll
    for (int m = 0; m < 4; ++m) {
        int n = tid + (m << 8);                 // 0..1023
        int rv = __brev((unsigned)n) >> 22;     // 10-bit reverse
        zr[rv] = xs[2 * n];
        zi[rv] = xs[2 * n + 1];
    }
    __syncthreads();

    // 10 radix-2 DIT stages on 1024 points (512 butterflies, 2/thread)
    for (int st = 1; st <= 10; ++st) {
        const int half = 1 << (st - 1);
        const int tsh = 11 - st;                // angle idx in 1/2048 units
#pragma unroll
        for (int s = 0; s < 2; ++s) {
            int idx = tid + (s << 8);           // 0..511
            int j = idx & (half - 1);
            int base = ((idx >> (st - 1)) << st) + j;
            int ti = j << tsh;
            float wr = ct[ti];
            float wi = -ct[(ti + 1536) & (NFFT - 1)];   // -sin
            float ar = zr[base], ai = zi[base];
            float br = zr[base + half], bi = zi[base + half];
            float tr = wr * br - wi * bi;
            float tq = wr * bi + wi * br;
            zr[base] = ar + tr;
            zi[base] = ai + tq;
            zr[base + half] = ar - tr;
            zi[base + half] = ai - tq;
        }
        __syncthreads();
    }

    // untangle: Re X_k = (a+c)/2 + cos*(b+d)/2 - sin*(a-c)/2
    float* ho = hh + (size_t)b * NHALF;
#pragma unroll
    for (int m = 0; m < 4; ++m) {
        int k = tid + (m << 8);
        int km = (NHALF - k) & (NHALF - 1);
        float a = zr[k], bb = zi[k];
        float c = zr[km], d = zi[km];
        float cosv = ct[k];
        float sinv = ct[(k + 1536) & (NFFT - 1)];
        ho[k] = 0.5f * ((a + c) + cosv * (bb + d) - sinv * (a - c));
    }
    if (tid == 0) h1024[b] = zr[0] - zi[0];
}

// ---------------- K2: partial GEMM yp[sp][b][j] = sum_{k in split} hh[b][k]*Wf[j][k]
__global__ __launch_bounds__(256) void k_gemm1(const float* __restrict__ hh,
                                               const float* __restrict__ Wf,
                                               float* __restrict__ yp) {
    __shared__ float Ws[32 * JP];
    __shared__ float hs[32 * HP];
    const int tid = threadIdx.x;
    const int b0 = blockIdx.x * BT;
    const int kb0 = blockIdx.y * KRANGE;

    const int j0 = (tid & 63) * 4;
    const int bo = (tid >> 6) * 8;

    float acc[8][4];
#pragma unroll
    for (int i = 0; i < 8; ++i)
#pragma unroll
        for (int q = 0; q < 4; ++q) acc[i][q] = 0.f;

    for (int kc = 0; kc < KRANGE; kc += 32) {
        const int kb = kb0 + kc;
#pragma unroll
        for (int s = 0; s < 8; ++s) {
            int f = tid + (s << 8);
            int j = f >> 3;
            int k4 = f & 7;
            float4 v = *(const float4*)(Wf + (size_t)j * NHALF + kb + k4 * 4);
            Ws[(k4 * 4 + 0) * JP + j] = v.x;
            Ws[(k4 * 4 + 1) * JP + j] = v.y;
            Ws[(k4 * 4 + 2) * JP + j] = v.z;
            Ws[(k4 * 4 + 3) * JP + j] = v.w;
        }
        {
            int bb = tid >> 3;
            int k4 = tid & 7;
            float4 v = *(const float4*)(hh + (size_t)(b0 + bb) * NHALF + kb + k4 * 4);
            hs[(k4 * 4 + 0) * HP + bb] = v.x;
            hs[(k4 * 4 + 1) * HP + bb] = v.y;
            hs[(k4 * 4 + 2) * HP + bb] = v.z;
            hs[(k4 * 4 + 3) * HP + bb] = v.w;
        }
        __syncthreads();

#pragma unroll 8
        for (int k = 0; k < 32; ++k) {
            float4 w = *(const float4*)&Ws[k * JP + j0];
            float4 hA = *(const float4*)&hs[k * HP + bo];
            float4 hB = *(const float4*)&hs[k * HP + bo + 4];
            acc[0][0] = fmaf(hA.x, w.x, acc[0][0]); acc[0][1] = fmaf(hA.x, w.y, acc[0][1]);
            acc[0][2] = fmaf(hA.x, w.z, acc[0][2]); acc[0][3] = fmaf(hA.x, w.w, acc[0][3]);
            acc[1][0] = fmaf(hA.y, w.x, acc[1][0]); acc[1][1] = fmaf(hA.y, w.y, acc[1][1]);
            acc[1][2] = fmaf(hA.y, w.z, acc[1][2]); acc[1][3] = fmaf(hA.y, w.w, acc[1][3]);
            acc[2][0] = fmaf(hA.z, w.x, acc[2][0]); acc[2][1] = fmaf(hA.z, w.y, acc[2][1]);
            acc[2][2] = fmaf(hA.z, w.z, acc[2][2]); acc[2][3] = fmaf(hA.z, w.w, acc[2][3]);
            acc[3][0] = fmaf(hA.w, w.x, acc[3][0]); acc[3][1] = fmaf(hA.w, w.y, acc[3][1]);
            acc[3][2] = fmaf(hA.w, w.z, acc[3][2]); acc[3][3] = fmaf(hA.w, w.w, acc[3][3]);
            acc[4][0] = fmaf(hB.x, w.x, acc[4][0]); acc[4][1] = fmaf(hB.x, w.y, acc[4][1]);
            acc[4][2] = fmaf(hB.x, w.z, acc[4][2]); acc[4][3] = fmaf(hB.x, w.w, acc[4][3]);
            acc[5][0] = fmaf(hB.y, w.x, acc[5][0]); acc[5][1] = fmaf(hB.y, w.y, acc[5][1]);
            acc[5][2] = fmaf(hB.y, w.z, acc[5][2]); acc[5][3] = fmaf(hB.y, w.w, acc[5][3]);
            acc[6][0] = fmaf(hB.z, w.x, acc[6][0]); acc[6][1] = fmaf(hB.z, w.y, acc[6][1]);
            acc[6][2] = fmaf(hB.z, w.z, acc[6][2]); acc[6][3] = fmaf(hB.z, w.w, acc[6][3]);
            acc[7][0] = fmaf(hB.w, w.x, acc[7][0]); acc[7][1] = fmaf(hB.w, w.y, acc[7][1]);
            acc[7][2] = fmaf(hB.w, w.z, acc[7][2]); acc[7][3] = fmaf(hB.w, w.w, acc[7][3]);
        }
        __syncthreads();
    }

    float* yo = yp + (size_t)blockIdx.y * (B * NH);
#pragma unroll
    for (int i = 0; i < 8; ++i) {
        float4 v = make_float4(acc[i][0], acc[i][1], acc[i][2], acc[i][3]);
        *(float4*)(yo + (size_t)(b0 + bo + i) * NH + j0) = v;
    }
}

// ---------------- K3: fused reduce + bias/relu + layer2 + layer3 + sigmoid ----------------
// One block per 4 batch rows.
__global__ __launch_bounds__(256) void k_tail(const float* __restrict__ yp,
                                              const float* __restrict__ b1,
                                              const float* __restrict__ Wc,
                                              const float* __restrict__ h1024,
                                              const float* __restrict__ W2,
                                              const float* __restrict__ b2,
                                              const float* __restrict__ W3,
                                              const float* __restrict__ b3,
                                              float* __restrict__ out) {
    __shared__ float ys[4 * NH];
    __shared__ float w2s[NH * 36];   // [j][k-chunk 32, pitch 36]
    __shared__ float red[4 * NH];
    const int tid = threadIdx.x;
    const int b0 = blockIdx.x * 4;

    // phase A: sum partials, + b1 + h1024*Wc, relu -> ys
    {
        int r = tid >> 6;
        int j = (tid & 63) * 4;
        const float* base = yp + (size_t)(b0 + r) * NH + j;
        float4 a = *(const float4*)(base);
#pragma unroll
        for (int s = 1; s < KSPLIT; ++s) {
            float4 v = *(const float4*)(base + (size_t)s * (B * NH));
            a.x += v.x; a.y += v.y; a.z += v.z; a.w += v.w;
        }
        float4 bb = *(const float4*)(b1 + j);
        float4 wc = *(const float4*)(Wc + j);
        float hq = h1024[b0 + r];
        a.x = fmaxf(a.x + bb.x + hq * wc.x, 0.f);
        a.y = fmaxf(a.y + bb.y + hq * wc.y, 0.f);
        a.z = fmaxf(a.z + bb.z + hq * wc.z, 0.f);
        a.w = fmaxf(a.w + bb.w + hq * wc.w, 0.f);
        *(float4*)(ys + r * NH + j) = a;
    }
    __syncthreads();

    // phase B: y2[r][tid] = sum_k ys[r][k] * W2[tid][k], chunked through LDS
    float a2[4] = {0.f, 0.f, 0.f, 0.f};
    for (int kc = 0; kc < NH; kc += 32) {
#pragma unroll
        for (int s = 0; s < 8; ++s) {
            int f = tid + (s << 8);
            int j = f >> 3;
            int k4 = f & 7;
            float4 v = *(const float4*)(W2 + (size_t)j * NH + kc + k4 * 4);
            *(float4*)(w2s + j * 36 + k4 * 4) = v;
        }
        __syncthreads();
#pragma unroll
        for (int k4 = 0; k4 < 8; ++k4) {
            float4 w = *(const float4*)(w2s + tid * 36 + k4 * 4);
#pragma unroll
            for (int r = 0; r < 4; ++r) {
                float4 y = *(const float4*)(ys + r * NH + kc + k4 * 4);
                a2[r] = fmaf(w.x, y.x, a2[r]);
                a2[r] = fmaf(w.y, y.y, a2[r]);
                a2[r] = fmaf(w.z, y.z, a2[r]);
                a2[r] = fmaf(w.w, y.w, a2[r]);
            }
        }
        __syncthreads();
    }

    // phase C: relu, scale by W3, tree-reduce, sigmoid
    float w3 = W3[tid];
    float bb2 = b2[tid];
#pragma unroll
    for (int r = 0; r < 4; ++r)
        red[r * NH + tid] = fmaxf(a2[r] + bb2, 0.f) * w3;
    __syncthreads();
    for (int s = 128; s > 0; s >>= 1) {
        if (tid < s) {
#pragma unroll
            for (int r = 0; r < 4; ++r)
                red[r * NH + tid] += red[r * NH + tid + s];
        }
        __syncthreads();
    }
    if (tid < 4)
        out[b0 + tid] = 1.f / (1.f + expf(-(red[tid * NH] + b3[0])));
}

extern "C" void kernel_launch(void* const* d_in, const int* in_sizes, int n_in,
                              void* d_out, int out_size, void* d_ws, size_t ws_size,
                              hipStream_t stream) {
    const float* x  = (const float*)d_in[0];
    const float* W1 = (const float*)d_in[1];
    const float* b1 = (const float*)d_in[2];
    const float* W2 = (const float*)d_in[3];
    const float* b2 = (const float*)d_in[4];
    const float* W3 = (const float*)d_in[5];
    const float* b3 = (const float*)d_in[6];
    float* out = (float*)d_out;

    char* ws = (char*)d_ws;
    float* hh    = (float*)(ws);                   //  4 MB [1024][1024]
    float* yp    = (float*)(ws + (4u  << 20));     // 16 MB [16][1024][256]
    float* Wf    = (float*)(ws + (20u << 20));     //  1 MB [256][1024]
    float* Wc    = (float*)(ws + (21u << 20));     //  1 KB [256]
    float* h1024 = (float*)(ws + (21u << 20) + 65536);  // 4 KB [1024]

    hipLaunchKernelGGL(k_fold,      dim3(1024),   dim3(256), 0, stream, W1, Wf, Wc);
    hipLaunchKernelGGL(k_mean_rfft, dim3(B),      dim3(256), 0, stream, x, hh, h1024);
    hipLaunchKernelGGL(k_gemm1,     dim3(32, 16), dim3(256), 0, stream, hh, Wf, yp);
    hipLaunchKernelGGL(k_tail,      dim3(256),    dim3(256), 0, stream, yp, b1, Wc, h1024,
                       W2, b2, W3, b3, out);
}